// Round 1
// baseline (504.865 us; speedup 1.0000x reference)
//
#include <hip/hip_runtime.h>
#include <math.h>

// Problem constants
#define N    130
#define NN   (130*130)
#define NNN  (130*130*130)
#define NCH  12
#define TOT  (NCH*NNN)
#define XN   128

// Per-channel z-shifts: z = p + sh, where sh = 2*a - 1 for one-hot index a in {0,1,2}.
// Derived from the 12 (i>j, dist^2==2) pairs of the 6-neighbourhood offsets.
__constant__ int SH1[12][3] = {
    { 1, 1,-1}, { 1,-1, 1}, { 1,-1, 1}, { 1, 1, 3}, { 1, 1, 3}, { 3, 1, 1},
    { 3, 1, 1}, { 3, 1, 1}, { 1, 3, 1}, { 1, 3, 1}, { 1, 3, 1}, { 1, 3, 1}
};
__constant__ int SH2[12][3] = {
    {-1, 1, 1}, {-1, 1, 1}, { 1, 1,-1}, {-1, 1, 1}, { 1,-1, 1}, { 1, 1,-1},
    { 1,-1, 1}, { 1, 1, 3}, {-1, 1, 1}, { 1, 1,-1}, { 1, 1, 3}, { 3, 1, 1}
};

// Sample the conv input: zero outside [0,132), else replication-padded x.
__device__ __forceinline__ float sampleX(const float* __restrict__ x,
                                         int zd, int zh, int zw) {
    if ((unsigned)zd > 131u || (unsigned)zh > 131u || (unsigned)zw > 131u)
        return 0.0f;  // conv zero-padding region
    int cd = min(max(zd - 2, 0), XN - 1);
    int ch = min(max(zh - 2, 0), XN - 1);
    int cw = min(max(zw - 2, 0), XN - 1);
    return x[(cd * XN + ch) * XN + cw];
}

// Kernel 1: squared shift-difference, [12,130,130,130]
__global__ __launch_bounds__(256) void k_sq(const float* __restrict__ x,
                                            float* __restrict__ sq) {
    int e = blockIdx.x * blockDim.x + threadIdx.x;
    if (e >= TOT) return;
    int o  = e / NNN;
    int r  = e - o * NNN;
    int d  = r / NN;
    int r2 = r - d * NN;
    int h  = r2 / N;
    int w  = r2 - h * N;
    float v1 = sampleX(x, d + SH1[o][0], h + SH1[o][1], w + SH1[o][2]);
    float v2 = sampleX(x, d + SH2[o][0], h + SH2[o][1], w + SH2[o][2]);
    float df = v1 - v2;
    sq[e] = df * df;
}

// Kernel 2: 5-tap box sum along W (edge-replicated)
__global__ __launch_bounds__(256) void k_passw(const float* __restrict__ in,
                                               float* __restrict__ out) {
    int e = blockIdx.x * blockDim.x + threadIdx.x;
    if (e >= TOT) return;
    int w    = e % N;
    int base = e - w;
    float s = 0.0f;
    #pragma unroll
    for (int dw = -2; dw <= 2; ++dw) {
        int ww = min(max(w + dw, 0), N - 1);
        s += in[base + ww];
    }
    out[e] = s;
}

// Kernel 3: 5-tap box sum along H (edge-replicated)
__global__ __launch_bounds__(256) void k_passh(const float* __restrict__ in,
                                               float* __restrict__ out) {
    int e = blockIdx.x * blockDim.x + threadIdx.x;
    if (e >= TOT) return;
    int h = (e / N) % N;
    float s = 0.0f;
    #pragma unroll
    for (int dh = -2; dh <= 2; ++dh) {
        int hh = min(max(h + dh, 0), N - 1);
        s += in[e + (hh - h) * N];
    }
    out[e] = s;
}

// Kernel 4: 5-tap box sum along D (edge-replicated) + 1/125 scale -> ssd
__global__ __launch_bounds__(256) void k_passd(const float* __restrict__ in,
                                               float* __restrict__ out) {
    int e = blockIdx.x * blockDim.x + threadIdx.x;
    if (e >= TOT) return;
    int d = (e / NN) % N;
    float s = 0.0f;
    #pragma unroll
    for (int dd = -2; dd <= 2; ++dd) {
        int ddc = min(max(d + dd, 0), N - 1);
        s += in[e + (ddc - d) * NN];
    }
    out[e] = s * (1.0f / 125.0f);
}

// Kernel 5a: zero the accumulator
__global__ void k_zero(double* acc) {
    if (blockIdx.x == 0 && threadIdx.x == 0) *acc = 0.0;
}

// Kernel 5b: sum of per-voxel mind_var = mean_ch(ssd) - min_ch(ssd)
__global__ __launch_bounds__(256) void k_red(const float* __restrict__ ssd,
                                             double* __restrict__ acc) {
    int q = blockIdx.x * blockDim.x + threadIdx.x;
    float local = 0.0f;
    if (q < NNN) {
        float v  = ssd[q];
        float mn = v, s = v;
        #pragma unroll
        for (int o = 1; o < NCH; ++o) {
            float vo = ssd[q + o * NNN];
            s += vo;
            mn = fminf(mn, vo);
        }
        local = s * (1.0f / 12.0f) - mn;
    }
    __shared__ float red[256];
    red[threadIdx.x] = local;
    __syncthreads();
    for (int st = 128; st > 0; st >>= 1) {
        if (threadIdx.x < st) red[threadIdx.x] += red[threadIdx.x + st];
        __syncthreads();
    }
    if (threadIdx.x == 0) atomicAdd(acc, (double)red[0]);
}

// Kernel 6: in-place min/mean/clip/exp epilogue over channels
__global__ __launch_bounds__(256) void k_final(float* __restrict__ ssd,
                                               const double* __restrict__ acc) {
    int q = blockIdx.x * blockDim.x + threadIdx.x;
    if (q >= NNN) return;
    float mv_mean = (float)(*acc * (1.0 / (double)NNN));
    float v[NCH];
    float mn = INFINITY, s = 0.0f;
    #pragma unroll
    for (int o = 0; o < NCH; ++o) {
        v[o] = ssd[q + o * NNN];
        s += v[o];
        mn = fminf(mn, v[o]);
    }
    float mvar = s * (1.0f / 12.0f) - mn;
    mvar = fminf(fmaxf(mvar, mv_mean * 0.001f), mv_mean * 1000.0f);
    float inv = 1.0f / mvar;
    #pragma unroll
    for (int o = 0; o < NCH; ++o) {
        ssd[q + o * NNN] = expf(-(v[o] - mn) * inv);
    }
}

extern "C" void kernel_launch(void* const* d_in, const int* in_sizes, int n_in,
                              void* d_out, int out_size, void* d_ws, size_t ws_size,
                              hipStream_t stream) {
    const float* x = (const float*)d_in[0];
    float* out = (float*)d_out;                 // [12,130,130,130] f32
    float* buf = (float*)d_ws;                  // 12*130^3 f32 = 105.5 MB
    double* acc = (double*)((char*)d_ws + (size_t)TOT * sizeof(float));

    const int BT = 256;
    const int gTOT = (TOT + BT - 1) / BT;
    const int gNNN = (NNN + BT - 1) / BT;

    k_sq   <<<gTOT, BT, 0, stream>>>(x, buf);        // sq -> ws
    k_passw<<<gTOT, BT, 0, stream>>>(buf, out);      // W box -> d_out
    k_passh<<<gTOT, BT, 0, stream>>>(out, buf);      // H box -> ws
    k_passd<<<gTOT, BT, 0, stream>>>(buf, out);      // D box + scale -> d_out (ssd)
    k_zero <<<1, 64, 0, stream>>>(acc);
    k_red  <<<gNNN, BT, 0, stream>>>(out, acc);      // sum(mind_var) -> acc
    k_final<<<gNNN, BT, 0, stream>>>(out, acc);      // in-place epilogue
}

// Round 2
// 384.846 us; speedup vs baseline: 1.3119x; 1.3119x over previous
//
#include <hip/hip_runtime.h>
#include <math.h>

// Problem constants
#define N    130
#define NN   (130*130)
#define NNN  (130*130*130)
#define NCH  12
#define TOT  (NCH*NNN)
#define XN   128
#define NB3  1024   // grid-stride block count for the fused D+reduce kernel

// Per-channel shifts into the 132^3 zero-padded/replication-padded coordinate
// system (verified in round 1): z = p + sh, sh in {-1,+1,+3}.
__constant__ int SH1[12][3] = {
    { 1, 1,-1}, { 1,-1, 1}, { 1,-1, 1}, { 1, 1, 3}, { 1, 1, 3}, { 3, 1, 1},
    { 3, 1, 1}, { 3, 1, 1}, { 1, 3, 1}, { 1, 3, 1}, { 1, 3, 1}, { 1, 3, 1}
};
__constant__ int SH2[12][3] = {
    {-1, 1, 1}, {-1, 1, 1}, { 1, 1,-1}, {-1, 1, 1}, { 1,-1, 1}, { 1, 1,-1},
    { 1,-1, 1}, { 1, 1, 3}, {-1, 1, 1}, { 1, 1,-1}, { 1, 1, 3}, { 3, 1, 1}
};

// Kernel 1: fused squared shift-difference + 5-tap W box sum.
// out[o,d,h,w] = sum_{dw=-2..2} diff^2(d, h, clamp(w+dw))
__global__ __launch_bounds__(256) void k_sqw(const float* __restrict__ x,
                                             float* __restrict__ out) {
    int e = blockIdx.x * 256 + threadIdx.x;
    if (e >= TOT) return;
    int o  = e / NNN;
    int r  = e - o * NNN;
    int d  = r / NN;
    int r2 = r - d * NN;
    int h  = r2 / N;
    int w  = r2 - h * N;

    int zd1 = d + SH1[o][0], zh1 = h + SH1[o][1], s1w = SH1[o][2];
    int zd2 = d + SH2[o][0], zh2 = h + SH2[o][1], s2w = SH2[o][2];
    bool ok1 = ((unsigned)zd1 <= 131u) && ((unsigned)zh1 <= 131u);
    bool ok2 = ((unsigned)zd2 <= 131u) && ((unsigned)zh2 <= 131u);
    const float* b1 = x + ((size_t)min(max(zd1 - 2, 0), XN - 1) * XN
                                 + min(max(zh1 - 2, 0), XN - 1)) * XN;
    const float* b2 = x + ((size_t)min(max(zd2 - 2, 0), XN - 1) * XN
                                 + min(max(zh2 - 2, 0), XN - 1)) * XN;
    float s = 0.0f;
    #pragma unroll
    for (int dw = -2; dw <= 2; ++dw) {
        int ww  = min(max(w + dw, 0), N - 1);
        int zw1 = ww + s1w, zw2 = ww + s2w;
        float v1 = (ok1 && (unsigned)zw1 <= 131u) ? b1[min(max(zw1 - 2, 0), XN - 1)] : 0.0f;
        float v2 = (ok2 && (unsigned)zw2 <= 131u) ? b2[min(max(zw2 - 2, 0), XN - 1)] : 0.0f;
        float df = v1 - v2;
        s += df * df;
    }
    out[e] = s;
}

// Kernel 2: 5-tap box sum along H (edge-replicated)
__global__ __launch_bounds__(256) void k_passh(const float* __restrict__ in,
                                               float* __restrict__ out) {
    int e = blockIdx.x * 256 + threadIdx.x;
    if (e >= TOT) return;
    int h = (e / N) % N;
    float s = 0.0f;
    #pragma unroll
    for (int dh = -2; dh <= 2; ++dh) {
        int hh = min(max(h + dh, 0), N - 1);
        s += in[e + (hh - h) * N];
    }
    out[e] = s;
}

// Kernel 3a: zero the accumulator
__global__ void k_zero(double* acc) {
    if (blockIdx.x == 0 && threadIdx.x == 0) *acc = 0.0;
}

// Kernel 3: fused D box + 1/125 scale -> ssd, plus per-voxel
// mind_var = mean_ch - min_ch partial reduction. Grid-stride over voxels,
// one f64 atomic per block (NB3 atomics total -> serialization hidden).
__global__ __launch_bounds__(256) void k_dred(const float* __restrict__ in,
                                              float* __restrict__ ssd,
                                              double* __restrict__ acc) {
    int tid = threadIdx.x;
    double local = 0.0;
    for (int q = blockIdx.x * 256 + tid; q < NNN; q += NB3 * 256) {
        int d    = q / NN;
        int base = q - d * NN;
        int dc[5];
        #pragma unroll
        for (int k = 0; k < 5; ++k)
            dc[k] = min(max(d + k - 2, 0), N - 1) * NN + base;
        float mn = INFINITY, sum = 0.0f;
        #pragma unroll
        for (int o = 0; o < NCH; ++o) {
            const float* po = in + (size_t)o * NNN;
            float s = po[dc[0]] + po[dc[1]] + po[dc[2]] + po[dc[3]] + po[dc[4]];
            s *= (1.0f / 125.0f);
            ssd[(size_t)o * NNN + q] = s;
            sum += s;
            mn = fminf(mn, s);
        }
        local += (double)(sum * (1.0f / 12.0f) - mn);
    }
    __shared__ double red[256];
    red[tid] = local;
    __syncthreads();
    for (int st = 128; st > 0; st >>= 1) {
        if (tid < st) red[tid] += red[tid + st];
        __syncthreads();
    }
    if (tid == 0) atomicAdd(acc, red[0]);
}

// Kernel 4: epilogue — min/mean/clip/exp over channels, ssd(ws) -> out
__global__ __launch_bounds__(256) void k_final(const float* __restrict__ ssd,
                                               const double* __restrict__ acc,
                                               float* __restrict__ out) {
    int q = blockIdx.x * 256 + threadIdx.x;
    if (q >= NNN) return;
    float mv_mean = (float)(*acc * (1.0 / (double)NNN));
    float v[NCH];
    float mn = INFINITY, s = 0.0f;
    #pragma unroll
    for (int o = 0; o < NCH; ++o) {
        v[o] = ssd[(size_t)o * NNN + q];
        s += v[o];
        mn = fminf(mn, v[o]);
    }
    float mvar = s * (1.0f / 12.0f) - mn;
    mvar = fminf(fmaxf(mvar, mv_mean * 0.001f), mv_mean * 1000.0f);
    float inv = 1.0f / mvar;
    #pragma unroll
    for (int o = 0; o < NCH; ++o) {
        out[(size_t)o * NNN + q] = expf(-(v[o] - mn) * inv);
    }
}

extern "C" void kernel_launch(void* const* d_in, const int* in_sizes, int n_in,
                              void* d_out, int out_size, void* d_ws, size_t ws_size,
                              hipStream_t stream) {
    const float* x = (const float*)d_in[0];
    float* out = (float*)d_out;                 // [12,130,130,130] f32
    float* buf = (float*)d_ws;                  // TOT floats = 105.5 MB
    double* acc = (double*)((char*)d_ws + (size_t)TOT * sizeof(float));

    const int BT = 256;
    const int gTOT = (TOT + BT - 1) / BT;
    const int gNNN = (NNN + BT - 1) / BT;

    k_sqw  <<<gTOT, BT, 0, stream>>>(x, buf);        // sq + W box -> ws
    k_passh<<<gTOT, BT, 0, stream>>>(buf, out);      // H box -> d_out
    k_zero <<<1, 64, 0, stream>>>(acc);
    k_dred <<<NB3, BT, 0, stream>>>(out, buf, acc);  // D box + reduce -> ssd in ws
    k_final<<<gNNN, BT, 0, stream>>>(buf, acc, out); // epilogue -> d_out
}

// Round 3
// 317.217 us; speedup vs baseline: 1.5915x; 1.2132x over previous
//
#include <hip/hip_runtime.h>
#include <math.h>

// Problem constants
#define N    130
#define NN   (130*130)
#define NNN  (130*130*130)
#define NCH  12
#define TOT  (NCH*NNN)
#define XN   128

// Tiling for the fused stencil kernel
#define TH   10            // H rows per workgroup slab (13 tiles exactly)
#define SD   26            // D depth per segment (5 segments exactly)
#define RH   (TH+4)        // 14 region rows
#define RW   (N+4)         // 134 region cols (full width + halo)
#define PL   (TH*N)        // 1300 plane elements
#define NBRED 1024         // blocks for the reduction kernel

// Per-channel shifts into the 132^3 padded coordinate system (verified R1/R2).
__constant__ int SH1[12][3] = {
    { 1, 1,-1}, { 1,-1, 1}, { 1,-1, 1}, { 1, 1, 3}, { 1, 1, 3}, { 3, 1, 1},
    { 3, 1, 1}, { 3, 1, 1}, { 1, 3, 1}, { 1, 3, 1}, { 1, 3, 1}, { 1, 3, 1}
};
__constant__ int SH2[12][3] = {
    {-1, 1, 1}, {-1, 1, 1}, { 1, 1,-1}, {-1, 1, 1}, { 1,-1, 1}, { 1, 1,-1},
    { 1,-1, 1}, { 1, 1, 3}, {-1, 1, 1}, { 1, 1,-1}, { 1, 1, 3}, { 3, 1, 1}
};

// Conv input sample: zero outside [0,132), else replication-clamped x.
__device__ __forceinline__ float sampleX(const float* __restrict__ x,
                                         int zd, int zh, int zw) {
    if ((unsigned)zd > 131u || (unsigned)zh > 131u || (unsigned)zw > 131u)
        return 0.0f;
    int cd = min(max(zd - 2, 0), XN - 1);
    int ch = min(max(zh - 2, 0), XN - 1);
    int cw = min(max(zw - 2, 0), XN - 1);
    return x[((size_t)cd * XN + ch) * XN + cw];
}

// Fused: diff^2 + W-box + H-box + D-box (all edge-replicated) -> ssd.
// One workgroup: channel o, H-slab [h0,h0+TH), D-segment [d0,d0+SD).
// Marches along D with a 5-plane LDS ring of HW-boxed diff^2 planes.
__global__ __launch_bounds__(256) void k_ssd(const float* __restrict__ x,
                                             float* __restrict__ ssd) {
    __shared__ float A[RH * RW];   // diff^2 region plane
    __shared__ float B[RH * N];    // W-boxed
    __shared__ float R[5][PL];     // ring of HW-boxed planes

    const int tid = threadIdx.x;
    const int b   = blockIdx.x;
    const int o   = b % NCH;
    const int r   = b / NCH;
    const int hT  = r % 13;
    const int dS  = r / 13;
    const int h0  = hT * TH;
    const int d0  = dS * SD;
    const int dend = d0 + SD - 1;

    const int s1d = SH1[o][0], s1h = SH1[o][1], s1w = SH1[o][2];
    const int s2d = SH2[o][0], s2h = SH2[o][1], s2w = SH2[o][2];

    // ---- plane compute lambda ----
    auto computePlane = [&](int dd) {
        // 1) diff^2 region
        for (int i = tid; i < RH * RW; i += 256) {
            int ih = i / RW, iw = i - ih * RW;
            int h = min(max(h0 + ih - 2, 0), N - 1);
            int w = min(max(iw - 2, 0), N - 1);
            float v1 = sampleX(x, dd + s1d, h + s1h, w + s1w);
            float v2 = sampleX(x, dd + s2d, h + s2h, w + s2w);
            float df = v1 - v2;
            A[i] = df * df;
        }
        __syncthreads();
        // 2) W box (5 contiguous taps)
        for (int i = tid; i < RH * N; i += 256) {
            int ih = i / N, iw = i - ih * N;
            const float* a = A + ih * RW + iw;
            B[i] = a[0] + a[1] + a[2] + a[3] + a[4];
        }
        __syncthreads();
        // 3) H box -> ring slot dd%5
        float* rp = R[dd % 5];
        for (int i = tid; i < PL; i += 256) {
            rp[i] = B[i] + B[i + N] + B[i + 2*N] + B[i + 3*N] + B[i + 4*N];
        }
        __syncthreads();
    };

    // init planes [max(d0-2,0), d0+2]
    for (int p = max(d0 - 2, 0); p <= d0 + 2; ++p) computePlane(p);

    for (int d = d0; d <= dend; ++d) {
        // D box over clamped ring slots (wave-uniform pointers)
        const float* r0 = R[min(max(d - 2, 0), N - 1) % 5];
        const float* r1 = R[min(max(d - 1, 0), N - 1) % 5];
        const float* r2 = R[d % 5];
        const float* r3 = R[min(d + 1, N - 1) % 5];
        const float* r4 = R[min(d + 2, N - 1) % 5];
        float* op = ssd + (size_t)o * NNN + (size_t)d * NN + (size_t)h0 * N;
        for (int i = tid; i < PL; i += 256) {
            float s = r0[i] + r1[i] + r2[i] + r3[i] + r4[i];
            op[i] = s * (1.0f / 125.0f);
        }
        // compute plane d+3 for next step (uniform condition; 2 barriers
        // inside computePlane separate this R-write from the reads above)
        int np = d + 3;
        if (d < dend && np <= N - 1) computePlane(np);
        else __syncthreads();
    }
}

// zero the accumulator
__global__ void k_zero(double* acc) {
    if (blockIdx.x == 0 && threadIdx.x == 0) *acc = 0.0;
}

// grid-stride reduction of mind_var = mean_ch(ssd) - min_ch(ssd)
__global__ __launch_bounds__(256) void k_red2(const float* __restrict__ ssd,
                                              double* __restrict__ acc) {
    int tid = threadIdx.x;
    double local = 0.0;
    for (int q = blockIdx.x * 256 + tid; q < NNN; q += NBRED * 256) {
        float v  = ssd[q];
        float mn = v, s = v;
        #pragma unroll
        for (int o = 1; o < NCH; ++o) {
            float vo = ssd[q + (size_t)o * NNN];
            s += vo;
            mn = fminf(mn, vo);
        }
        local += (double)(s * (1.0f / 12.0f) - mn);
    }
    __shared__ double red[256];
    red[tid] = local;
    __syncthreads();
    for (int st = 128; st > 0; st >>= 1) {
        if (tid < st) red[tid] += red[tid + st];
        __syncthreads();
    }
    if (tid == 0) atomicAdd(acc, red[0]);
}

// epilogue: min/mean/clip/exp over channels, ssd(ws) -> out
__global__ __launch_bounds__(256) void k_final(const float* __restrict__ ssd,
                                               const double* __restrict__ acc,
                                               float* __restrict__ out) {
    int q = blockIdx.x * 256 + threadIdx.x;
    if (q >= NNN) return;
    float mv_mean = (float)(*acc * (1.0 / (double)NNN));
    float v[NCH];
    float mn = INFINITY, s = 0.0f;
    #pragma unroll
    for (int o = 0; o < NCH; ++o) {
        v[o] = ssd[(size_t)o * NNN + q];
        s += v[o];
        mn = fminf(mn, v[o]);
    }
    float mvar = s * (1.0f / 12.0f) - mn;
    mvar = fminf(fmaxf(mvar, mv_mean * 0.001f), mv_mean * 1000.0f);
    float inv = 1.0f / mvar;
    #pragma unroll
    for (int o = 0; o < NCH; ++o) {
        out[(size_t)o * NNN + q] = expf(-(v[o] - mn) * inv);
    }
}

extern "C" void kernel_launch(void* const* d_in, const int* in_sizes, int n_in,
                              void* d_out, int out_size, void* d_ws, size_t ws_size,
                              hipStream_t stream) {
    const float* x = (const float*)d_in[0];
    float* out = (float*)d_out;                 // [12,130,130,130] f32
    float* buf = (float*)d_ws;                  // TOT floats = 105.5 MB (ssd)
    double* acc = (double*)((char*)d_ws + (size_t)TOT * sizeof(float));

    const int BT = 256;
    const int gNNN = (NNN + BT - 1) / BT;
    const int gSSD = NCH * 13 * 5;              // 780 workgroups

    k_ssd  <<<gSSD, BT, 0, stream>>>(x, buf);        // fused stencil -> ssd in ws
    k_zero <<<1, 64, 0, stream>>>(acc);
    k_red2 <<<NBRED, BT, 0, stream>>>(buf, acc);     // mind_var sum
    k_final<<<gNNN, BT, 0, stream>>>(buf, acc, out); // epilogue -> d_out
}

// Round 4
// 296.256 us; speedup vs baseline: 1.7041x; 1.0708x over previous
//
#include <hip/hip_runtime.h>
#include <math.h>

// Problem constants
#define N    130
#define NN   (130*130)       // 16900
#define NNN  (130*130*130)   // 2197000
#define NCH  12
#define TOT  (NCH*NNN)
#define XN   128
#define XNN  (XN*XN)

#define CHUNKS 67            // ceil(NN/256) column chunks
#define TH2  13              // h-rows per K2 segment (10 segments)
#define NSEG 10

// Per-channel shifts into the 132^3 padded coordinate system (verified R1-R3).
__constant__ int SH1[12][3] = {
    { 1, 1,-1}, { 1,-1, 1}, { 1,-1, 1}, { 1, 1, 3}, { 1, 1, 3}, { 3, 1, 1},
    { 3, 1, 1}, { 3, 1, 1}, { 1, 3, 1}, { 1, 3, 1}, { 1, 3, 1}, { 1, 3, 1}
};
__constant__ int SH2[12][3] = {
    {-1, 1, 1}, {-1, 1, 1}, { 1, 1,-1}, {-1, 1, 1}, { 1,-1, 1}, { 1, 1,-1},
    { 1,-1, 1}, { 1, 1, 3}, {-1, 1, 1}, { 1, 1,-1}, { 1, 1, 3}, { 3, 1, 1}
};

// K1: D-boxed squared shift-difference.
// C(o,d,h,w) = sum_{dd=-2..2} diff^2(cl(d+dd), h, w)   (register ring along d)
__global__ __launch_bounds__(256) void k_dbox(const float* __restrict__ x,
                                              float* __restrict__ C) {
    const int b = blockIdx.x;
    const int o = b / CHUNKS;          // uniform per block
    const int chunk = b - o * CHUNKS;
    int ci = chunk * 256 + threadIdx.x;
    const bool active = (ci < NN);
    if (!active) ci = 0;
    const int h = ci / N;
    const int w = ci - h * N;

    const int s1d = SH1[o][0], s1h = SH1[o][1], s1w = SH1[o][2];
    const int s2d = SH2[o][0], s2h = SH2[o][1], s2w = SH2[o][2];

    // h/w-dependent parts are d-invariant: precompute offsets + masks once.
    const int zh1 = h + s1h, zw1 = w + s1w;
    const int zh2 = h + s2h, zw2 = w + s2w;
    const float m1 = ((unsigned)zh1 <= 131u && (unsigned)zw1 <= 131u) ? 1.0f : 0.0f;
    const float m2 = ((unsigned)zh2 <= 131u && (unsigned)zw2 <= 131u) ? 1.0f : 0.0f;
    const int off1 = min(max(zh1 - 2, 0), XN - 1) * XN + min(max(zw1 - 2, 0), XN - 1);
    const int off2 = min(max(zh2 - 2, 0), XN - 1) * XN + min(max(zw2 - 2, 0), XN - 1);

    auto dsq = [&](int dd) -> float {
        int zd1 = dd + s1d, zd2 = dd + s2d;
        float v1 = x[(size_t)(min(max(zd1 - 2, 0), XN - 1)) * XNN + off1];
        float v2 = x[(size_t)(min(max(zd2 - 2, 0), XN - 1)) * XNN + off2];
        v1 *= ((unsigned)zd1 <= 131u) ? m1 : 0.0f;
        v2 *= ((unsigned)zd2 <= 131u) ? m2 : 0.0f;
        float df = v1 - v2;
        return df * df;
    };

    float r2 = dsq(0);
    float r0 = r2, r1 = r2;
    float r3 = dsq(1);
    float r4 = dsq(2);

    float* Cp = C + (size_t)o * NNN + ci;
    for (int d = 0; d < N; ++d) {
        if (active) Cp[(size_t)d * NN] = r0 + r1 + r2 + r3 + r4;
        r0 = r1; r1 = r2; r2 = r3; r3 = r4;
        r4 = (d + 3 <= N - 1) ? dsq(d + 3) : r3;   // clamp: reuse dsq(129)
    }
}

// zero the accumulator
__global__ void k_zero(double* acc) {
    if (blockIdx.x == 0 && threadIdx.x == 0) *acc = 0.0;
}

// K2: W-box + H-box (register ring along h) for ALL 12 channels per thread,
// then per-voxel min/mean: write mind = ssd - min to `mind` (output layout),
// block-reduce sum(mind_var) into acc.
__global__ __launch_bounds__(256) void k_hwred(const float* __restrict__ C,
                                               float* __restrict__ mind,
                                               double* __restrict__ acc) {
    const int b = blockIdx.x;
    const int seg = b / CHUNKS;
    const int chunk = b - seg * CHUNKS;
    int ci = chunk * 256 + threadIdx.x;        // column over (d,w)
    const bool active = (ci < NN);
    if (!active) ci = 0;
    const int d = ci / N;
    const int w = ci - d * N;
    const int h0 = seg * TH2;

    // w-tap relative offsets (clamped at the w borders), d-invariant
    const int t0 = max(w - 2, 0) - w;
    const int t1 = max(w - 1, 0) - w;
    const int t3 = min(w + 1, N - 1) - w;
    const int t4 = min(w + 2, N - 1) - w;

    const int colbase = d * NN + w;

    float r[NCH][5];

    // W-boxed value at row h' for channel o
    auto lw = [&](int o, int hh) -> float {
        const float* p = C + (size_t)o * NNN + colbase + hh * N;
        return p[t0] + p[t1] + p[0] + p[t3] + p[t4];
    };

    // warmup ring: rows cl(h0-2), cl(h0-1), h0, h0+1, h0+2
    {
        const int hw0 = max(h0 - 2, 0);
        const int hw1 = max(h0 - 1, 0);
        #pragma unroll
        for (int o = 0; o < NCH; ++o) {
            r[o][0] = lw(o, hw0);
            r[o][1] = lw(o, hw1);
            r[o][2] = lw(o, h0);
            r[o][3] = lw(o, h0 + 1);
            r[o][4] = lw(o, h0 + 2);
        }
    }

    float lsum = 0.0f;
    for (int h = h0; h < h0 + TH2; ++h) {
        float sv[NCH];
        float mn = INFINITY, tot = 0.0f;
        #pragma unroll
        for (int o = 0; o < NCH; ++o) {
            float s = (r[o][0] + r[o][1] + r[o][2] + r[o][3] + r[o][4]) * (1.0f / 125.0f);
            sv[o] = s;
            tot += s;
            mn = fminf(mn, s);
        }
        if (active) {
            const size_t vox = (size_t)d * NN + (size_t)h * N + w;
            #pragma unroll
            for (int o = 0; o < NCH; ++o)
                mind[(size_t)o * NNN + vox] = sv[o] - mn;
            lsum += tot * (1.0f / 12.0f) - mn;     // mind_var
        }
        // advance ring: append row cl(h+3)
        if (h + 3 <= N - 1) {
            #pragma unroll
            for (int o = 0; o < NCH; ++o) {
                r[o][0] = r[o][1]; r[o][1] = r[o][2];
                r[o][2] = r[o][3]; r[o][3] = r[o][4];
                r[o][4] = lw(o, h + 3);
            }
        } else {
            #pragma unroll
            for (int o = 0; o < NCH; ++o) {
                r[o][0] = r[o][1]; r[o][1] = r[o][2];
                r[o][2] = r[o][3]; r[o][3] = r[o][4];
                // r[o][4] keeps = row 129 value (already newest)
            }
        }
    }

    __shared__ float red[256];
    red[threadIdx.x] = lsum;
    __syncthreads();
    for (int st = 128; st > 0; st >>= 1) {
        if (threadIdx.x < st) red[threadIdx.x] += red[threadIdx.x + st];
        __syncthreads();
    }
    if (threadIdx.x == 0) atomicAdd(acc, (double)red[0]);
}

// K3: in-place epilogue on d_out. mvar = mean_ch(mind) (== mean(ssd)-min),
// clip by global mean, exp.
__global__ __launch_bounds__(256) void k_exp(float* __restrict__ io,
                                             const double* __restrict__ acc) {
    int q = blockIdx.x * 256 + threadIdx.x;
    if (q >= NNN) return;
    float mv_mean = (float)(*acc * (1.0 / (double)NNN));
    float v[NCH];
    float tot = 0.0f;
    #pragma unroll
    for (int o = 0; o < NCH; ++o) {
        v[o] = io[(size_t)o * NNN + q];
        tot += v[o];
    }
    float mvar = tot * (1.0f / 12.0f);
    mvar = fminf(fmaxf(mvar, mv_mean * 0.001f), mv_mean * 1000.0f);
    float inv = 1.0f / mvar;
    #pragma unroll
    for (int o = 0; o < NCH; ++o)
        io[(size_t)o * NNN + q] = expf(-v[o] * inv);
}

extern "C" void kernel_launch(void* const* d_in, const int* in_sizes, int n_in,
                              void* d_out, int out_size, void* d_ws, size_t ws_size,
                              hipStream_t stream) {
    const float* x = (const float*)d_in[0];
    float* out = (float*)d_out;                 // [12,130,130,130] f32
    float* C   = (float*)d_ws;                  // TOT floats = 105.5 MB
    double* acc = (double*)((char*)d_ws + (size_t)TOT * sizeof(float));

    const int BT = 256;
    k_dbox <<<NCH * CHUNKS, BT, 0, stream>>>(x, C);       // 804 blocks
    k_zero <<<1, 64, 0, stream>>>(acc);
    k_hwred<<<NSEG * CHUNKS, BT, 0, stream>>>(C, out, acc); // 670 blocks
    k_exp  <<<(NNN + BT - 1) / BT, BT, 0, stream>>>(out, acc);
}

// Round 5
// 248.994 us; speedup vs baseline: 2.0276x; 1.1898x over previous
//
#include <hip/hip_runtime.h>
#include <math.h>

// Problem constants
#define N    130
#define NN   (130*130)       // 16900
#define NNN  (130*130*130)   // 2197000
#define NCH  12
#define TOT  (NCH*NNN)
#define XN   128
#define XNN  (XN*XN)

#define CHUNKS 67            // ceil(NN/256) column chunks
#define DSEG 2               // d-segments in K1
#define DL   65              // d rows per segment
#define TH2  10              // h rows per K2 segment
#define NSEG 13              // 130/TH2

// Per-channel shifts into the 132^3 padded coordinate system (verified R1-R4).
__constant__ int SH1[12][3] = {
    { 1, 1,-1}, { 1,-1, 1}, { 1,-1, 1}, { 1, 1, 3}, { 1, 1, 3}, { 3, 1, 1},
    { 3, 1, 1}, { 3, 1, 1}, { 1, 3, 1}, { 1, 3, 1}, { 1, 3, 1}, { 1, 3, 1}
};
__constant__ int SH2[12][3] = {
    {-1, 1, 1}, {-1, 1, 1}, { 1, 1,-1}, {-1, 1, 1}, { 1,-1, 1}, { 1, 1,-1},
    { 1,-1, 1}, { 1, 1, 3}, {-1, 1, 1}, { 1, 1,-1}, { 1, 1, 3}, { 3, 1, 1}
};

// K1: diff^2 + W-box + D-box -> CW[o][d][h][w]
// Thread = (h,w) column for one channel & d-segment; register ring along d.
// Per d-plane: wsq(d) = sum_{t=0..4} diff^2(d, h, cl(w+t-2)); out = 5-plane ring sum.
__global__ __launch_bounds__(256) void k_dwbox(const float* __restrict__ x,
                                               float* __restrict__ CW) {
    const int b = blockIdx.x;
    const int chunk = b % CHUNKS;
    const int r  = b / CHUNKS;
    const int ds = r % DSEG;
    const int o  = r / DSEG;           // uniform per block
    int ci = chunk * 256 + threadIdx.x;
    const bool active = (ci < NN);
    if (!active) ci = 0;
    const int h = ci / N;
    const int w = ci - h * N;
    const int d0 = ds * DL;

    const int s1d = SH1[o][0], s1h = SH1[o][1], s1w = SH1[o][2];
    const int s2d = SH2[o][0], s2h = SH2[o][1], s2w = SH2[o][2];

    // d-invariant per-tap offsets and masks (h and the 5 clamped w-taps)
    const int zh1 = h + s1h, zh2 = h + s2h;
    const bool h1ok = (unsigned)zh1 <= 131u;
    const bool h2ok = (unsigned)zh2 <= 131u;
    const int hb1 = min(max(zh1 - 2, 0), XN - 1) * XN;
    const int hb2 = min(max(zh2 - 2, 0), XN - 1) * XN;
    int   o1[5], o2[5];
    float m1[5], m2[5];
    #pragma unroll
    for (int t = 0; t < 5; ++t) {
        int wt  = min(max(w + t - 2, 0), N - 1);
        int zw1 = wt + s1w, zw2 = wt + s2w;
        m1[t] = (h1ok && (unsigned)zw1 <= 131u) ? 1.0f : 0.0f;
        m2[t] = (h2ok && (unsigned)zw2 <= 131u) ? 1.0f : 0.0f;
        o1[t] = hb1 + min(max(zw1 - 2, 0), XN - 1);
        o2[t] = hb2 + min(max(zw2 - 2, 0), XN - 1);
    }

    // W-boxed squared diff at plane dd
    auto wsq = [&](int dd) -> float {
        int zd1 = dd + s1d, zd2 = dd + s2d;
        const float* b1 = x + (size_t)min(max(zd1 - 2, 0), XN - 1) * XNN;
        const float* b2 = x + (size_t)min(max(zd2 - 2, 0), XN - 1) * XNN;
        float f1 = ((unsigned)zd1 <= 131u) ? 1.0f : 0.0f;
        float f2 = ((unsigned)zd2 <= 131u) ? 1.0f : 0.0f;
        float s = 0.0f;
        #pragma unroll
        for (int t = 0; t < 5; ++t) {
            float v1 = b1[o1[t]] * (m1[t] * f1);
            float v2 = b2[o2[t]] * (m2[t] * f2);
            float df = v1 - v2;
            s += df * df;
        }
        return s;
    };

    // ring warmup: planes cl(d0-2), cl(d0-1), d0, d0+1, d0+2
    float r0 = wsq(max(d0 - 2, 0));
    float r1 = wsq(max(d0 - 1, 0));
    float r2 = wsq(d0);
    float r3 = wsq(d0 + 1);
    float r4 = wsq(d0 + 2);

    float* Cp = CW + (size_t)o * NNN + ci;
    for (int d = d0; d < d0 + DL; ++d) {
        if (active) Cp[(size_t)d * NN] = r0 + r1 + r2 + r3 + r4;
        r0 = r1; r1 = r2; r2 = r3; r3 = r4;
        r4 = (d + 3 <= N - 1) ? wsq(d + 3) : r3;   // clamp: plane 129 again
    }
}

// zero the accumulator
__global__ void k_zero(double* acc) {
    if (blockIdx.x == 0 && threadIdx.x == 0) *acc = 0.0;
}

// K2: H-box (register ring along h, single load per append) for all 12
// channels, per-voxel min/mean, write mind = ssd - min, reduce mind_var.
__global__ __launch_bounds__(256) void k_hred(const float* __restrict__ CW,
                                              float* __restrict__ mind,
                                              double* __restrict__ acc) {
    const int b = blockIdx.x;
    const int seg = b / CHUNKS;
    const int chunk = b - seg * CHUNKS;
    int ci = chunk * 256 + threadIdx.x;        // column over (d,w)
    const bool active = (ci < NN);
    if (!active) ci = 0;
    const int d = ci / N;
    const int w = ci - d * N;
    const int h0 = seg * TH2;
    const int colbase = d * NN + w;

    float rg[NCH][5];

    auto lw = [&](int o, int hh) -> float {
        return CW[(size_t)o * NNN + colbase + hh * N];
    };

    {
        const int hw0 = max(h0 - 2, 0);
        const int hw1 = max(h0 - 1, 0);
        #pragma unroll
        for (int o = 0; o < NCH; ++o) {
            rg[o][0] = lw(o, hw0);
            rg[o][1] = lw(o, hw1);
            rg[o][2] = lw(o, h0);
            rg[o][3] = lw(o, h0 + 1);
            rg[o][4] = lw(o, h0 + 2);
        }
    }

    float lsum = 0.0f;
    for (int h = h0; h < h0 + TH2; ++h) {
        float sv[NCH];
        float mn = INFINITY, tot = 0.0f;
        #pragma unroll
        for (int o = 0; o < NCH; ++o) {
            float s = (rg[o][0] + rg[o][1] + rg[o][2] + rg[o][3] + rg[o][4])
                      * (1.0f / 125.0f);
            sv[o] = s;
            tot += s;
            mn = fminf(mn, s);
        }
        if (active) {
            const size_t vox = (size_t)d * NN + (size_t)h * N + w;
            #pragma unroll
            for (int o = 0; o < NCH; ++o)
                mind[(size_t)o * NNN + vox] = sv[o] - mn;
            lsum += tot * (1.0f / 12.0f) - mn;     // mind_var
        }
        const bool more = (h + 3 <= N - 1);
        #pragma unroll
        for (int o = 0; o < NCH; ++o) {
            rg[o][0] = rg[o][1]; rg[o][1] = rg[o][2];
            rg[o][2] = rg[o][3]; float last = rg[o][4];
            rg[o][3] = last;
            rg[o][4] = more ? lw(o, h + 3) : last;
        }
    }

    __shared__ float red[256];
    red[threadIdx.x] = lsum;
    __syncthreads();
    for (int st = 128; st > 0; st >>= 1) {
        if (threadIdx.x < st) red[threadIdx.x] += red[threadIdx.x + st];
        __syncthreads();
    }
    if (threadIdx.x == 0) atomicAdd(acc, (double)red[0]);
}

// K3: in-place epilogue on d_out. mvar = mean_ch(mind), clip, exp.
__global__ __launch_bounds__(256) void k_exp(float* __restrict__ io,
                                             const double* __restrict__ acc) {
    int q = blockIdx.x * 256 + threadIdx.x;
    if (q >= NNN) return;
    float mv_mean = (float)(*acc * (1.0 / (double)NNN));
    float v[NCH];
    float tot = 0.0f;
    #pragma unroll
    for (int o = 0; o < NCH; ++o) {
        v[o] = io[(size_t)o * NNN + q];
        tot += v[o];
    }
    float mvar = tot * (1.0f / 12.0f);
    mvar = fminf(fmaxf(mvar, mv_mean * 0.001f), mv_mean * 1000.0f);
    float inv = 1.0f / mvar;
    #pragma unroll
    for (int o = 0; o < NCH; ++o)
        io[(size_t)o * NNN + q] = expf(-v[o] * inv);
}

extern "C" void kernel_launch(void* const* d_in, const int* in_sizes, int n_in,
                              void* d_out, int out_size, void* d_ws, size_t ws_size,
                              hipStream_t stream) {
    const float* x = (const float*)d_in[0];
    float* out = (float*)d_out;                 // [12,130,130,130] f32
    float* CW  = (float*)d_ws;                  // TOT floats = 105.5 MB
    double* acc = (double*)((char*)d_ws + (size_t)TOT * sizeof(float));

    const int BT = 256;
    k_dwbox<<<NCH * DSEG * CHUNKS, BT, 0, stream>>>(x, CW);   // 1608 blocks
    k_zero <<<1, 64, 0, stream>>>(acc);
    k_hred <<<NSEG * CHUNKS, BT, 0, stream>>>(CW, out, acc);  // 871 blocks
    k_exp  <<<(NNN + BT - 1) / BT, BT, 0, stream>>>(out, acc);
}